// Round 1
// baseline (2200.606 us; speedup 1.0000x reference)
//
#include <hip/hip_runtime.h>

#define NROWS   2000000
#define FEAT    83
#define DIMF    64
#define LAT     32
#define TILE    128     // rows per block
#define THREADS 128     // 2 waves

__global__ __launch_bounds__(THREADS, 2)
void material_encoder_kernel(const float* __restrict__ inp,
                             const float* __restrict__ shiftp,
                             const float* __restrict__ W1,
                             const float* __restrict__ b1,
                             const float* __restrict__ Wh0,
                             const float* __restrict__ bh0,
                             const float* __restrict__ Wh1,
                             const float* __restrict__ bh1,
                             float* __restrict__ out,
                             int nrows)
{
    // Union buffer: x tile (128*83 fp32 = 42496 B), then h (stride 65), then g (stride 33)
    __shared__ float lds[TILE * FEAT];

    const int t = threadIdx.x;
    const long long row0 = (long long)blockIdx.x * TILE;

    // ---- stage x tile: contiguous TILE*FEAT floats, coalesced float4 ----
    {
        const float4* __restrict__ src = (const float4*)(inp + row0 * FEAT);
        float4* dst = (float4*)lds;
        const int nvec = TILE * FEAT / 4;          // 2656
        #pragma unroll
        for (int i = 0; i < nvec / THREADS; ++i)   // 20 full rounds
            dst[i * THREADS + t] = src[i * THREADS + t];
        const int base = (nvec / THREADS) * THREADS;   // 2560
        if (t < nvec - base)                        // 96 remainder
            dst[base + t] = src[base + t];
    }
    __syncthreads();

    const float sh = shiftp[0];

    // ---- layer 1: h[64] = relu(x @ W1 + b1), x = raw + shift ----
    float h[DIMF];
    #pragma unroll
    for (int k = 0; k < DIMF; ++k) h[k] = b1[k];

    bool nz = false;
    const float* xrow = lds + t * FEAT;   // bank stride 83 (odd*): 2 lanes/bank = free
    float xj = xrow[0];
    #pragma unroll 1
    for (int j = 0; j < FEAT; ++j) {
        float xnext = (j + 1 < FEAT) ? xrow[j + 1] : 0.0f;  // software prefetch
        nz |= (xj != 0.0f);
        const float xs = xj + sh;
        const float* __restrict__ wrow = W1 + j * DIMF;     // wave-uniform -> s_load
        #pragma unroll
        for (int k = 0; k < DIMF; ++k)
            h[k] = fmaf(xs, wrow[k], h[k]);
        xj = xnext;
    }
    #pragma unroll
    for (int k = 0; k < DIMF; ++k) h[k] = fmaxf(h[k], 0.0f);

    __syncthreads();   // all x reads complete before overwriting buffer with h

    // h -> LDS at odd stride 65 (dynamic k indexing must come from memory, not regs)
    #pragma unroll
    for (int k = 0; k < DIMF; ++k) lds[t * 65 + k] = h[k];
    // each thread reads only its own row -> no barrier needed before reads

    // ---- layer 2: g[32] = relu(h @ Wh0 + bh0) ----
    float g[LAT];
    #pragma unroll
    for (int m = 0; m < LAT; ++m) g[m] = bh0[m];

    {
        float hk = lds[t * 65];
        #pragma unroll 1
        for (int k = 0; k < DIMF; ++k) {
            float hnext = (k + 1 < DIMF) ? lds[t * 65 + k + 1] : 0.0f;
            const float* __restrict__ wrow = Wh0 + k * LAT;  // uniform -> s_load
            #pragma unroll
            for (int m = 0; m < LAT; ++m)
                g[m] = fmaf(hk, wrow[m], g[m]);
            hk = hnext;
        }
    }
    #pragma unroll
    for (int m = 0; m < LAT; ++m) g[m] = fmaxf(g[m], 0.0f);

    __syncthreads();   // all h reads complete before overwriting buffer with g

    #pragma unroll
    for (int m = 0; m < LAT; ++m) lds[t * 33 + m] = g[m];

    // ---- layer 3: e[32] = relu(g @ Wh1 + bh1) ----
    float e[LAT];
    #pragma unroll
    for (int m = 0; m < LAT; ++m) e[m] = bh1[m];

    {
        float gq = lds[t * 33];
        #pragma unroll 1
        for (int q = 0; q < LAT; ++q) {
            float gnext = (q + 1 < LAT) ? lds[t * 33 + q + 1] : 0.0f;
            const float* __restrict__ wrow = Wh1 + q * LAT;  // uniform -> s_load
            #pragma unroll
            for (int m = 0; m < LAT; ++m)
                e[m] = fmaf(gq, wrow[m], e[m]);
            gq = gnext;
        }
    }

    // ---- relu + L2 normalize + mask ----
    float ss = 0.0f;
    #pragma unroll
    for (int m = 0; m < LAT; ++m) {
        e[m] = fmaxf(e[m], 0.0f);
        ss = fmaf(e[m], e[m], ss);
    }
    const float norm = sqrtf(ss);
    const float scale = nz ? (1.0f / fmaxf(norm, 1e-12f)) : 0.0f;

    // ---- write 3 identical copies, float4 per thread ----
    float4 v[8];
    #pragma unroll
    for (int q = 0; q < 8; ++q) {
        v[q].x = e[q * 4 + 0] * scale;
        v[q].y = e[q * 4 + 1] * scale;
        v[q].z = e[q * 4 + 2] * scale;
        v[q].w = e[q * 4 + 3] * scale;
    }
    const long long obase = (row0 + t) * LAT;
    float4* o0 = (float4*)(out + obase);
    float4* o1 = (float4*)(out + (long long)NROWS * LAT + obase);
    float4* o2 = (float4*)(out + 2LL * (long long)NROWS * LAT + obase);
    #pragma unroll
    for (int q = 0; q < 8; ++q) o0[q] = v[q];
    #pragma unroll
    for (int q = 0; q < 8; ++q) o1[q] = v[q];
    #pragma unroll
    for (int q = 0; q < 8; ++q) o2[q] = v[q];
}

extern "C" void kernel_launch(void* const* d_in, const int* in_sizes, int n_in,
                              void* d_out, int out_size, void* d_ws, size_t ws_size,
                              hipStream_t stream) {
    const float* inp    = (const float*)d_in[0];
    const float* shiftp = (const float*)d_in[1];
    const float* W1     = (const float*)d_in[2];
    const float* b1     = (const float*)d_in[3];
    const float* Wh0    = (const float*)d_in[4];
    const float* bh0    = (const float*)d_in[5];
    const float* Wh1    = (const float*)d_in[6];
    const float* bh1    = (const float*)d_in[7];
    float* out = (float*)d_out;

    const int nrows = in_sizes[0] / FEAT;      // 2,000,000
    const int tiles = nrows / TILE;            // 15625 (exact)

    material_encoder_kernel<<<dim3(tiles), dim3(THREADS), 0, stream>>>(
        inp, shiftp, W1, b1, Wh0, bh0, Wh1, bh1, out, nrows);
}

// Round 2
// 772.942 us; speedup vs baseline: 2.8471x; 2.8471x over previous
//
#include <hip/hip_runtime.h>

#define FEAT    83
#define DIMF    64
#define LAT     32
#define THREADS 256

__global__ __launch_bounds__(THREADS, 4)
void material_encoder_kernel(const float* __restrict__ inp,
                             const float* __restrict__ shiftp,
                             const float* __restrict__ W1,
                             const float* __restrict__ b1,
                             const float* __restrict__ Wh0,
                             const float* __restrict__ bh0,
                             const float* __restrict__ Wh1,
                             const float* __restrict__ bh1,
                             float* __restrict__ out,
                             int nrows)
{
    const int row = blockIdx.x * THREADS + threadIdx.x;
    if (row >= nrows) return;

    const float sh = shiftp[0];
    const float* __restrict__ xg = inp + (long long)row * FEAT;

    // ---- layer 1: h[64] = relu((x+shift) @ W1 + b1), x streamed from global ----
    float h[DIMF];
    #pragma unroll
    for (int k = 0; k < DIMF; ++k) h[k] = b1[k];   // uniform -> s_load

    unsigned nzbits = 0u;   // or of (bits<<1): nonzero iff any x != +-0

    float xa[8], xb[8];
    #pragma unroll
    for (int i = 0; i < 8; ++i) xa[i] = xg[i];

    #pragma unroll 1
    for (int jb = 0; jb < 72; jb += 8) {
        // prefetch next batch (vmcnt wait falls AFTER the FMAs below)
        #pragma unroll
        for (int i = 0; i < 8; ++i) xb[i] = xg[jb + 8 + i];

        float xs[8];
        #pragma unroll
        for (int i = 0; i < 8; ++i) {
            nzbits |= (__float_as_uint(xa[i]) << 1);
            xs[i] = xa[i] + sh;
        }
        const float* __restrict__ w = W1 + jb * DIMF;   // uniform -> s_load
        #pragma unroll
        for (int k = 0; k < DIMF; ++k) {
            float acc = h[k];
            #pragma unroll
            for (int i = 0; i < 8; ++i)
                acc = fmaf(xs[i], w[i * DIMF + k], acc);
            h[k] = acc;
        }
        #pragma unroll
        for (int i = 0; i < 8; ++i) xa[i] = xb[i];      // renamed away
    }
    {   // last full batch j = 72..79 (already in xa)
        float xs[8];
        #pragma unroll
        for (int i = 0; i < 8; ++i) {
            nzbits |= (__float_as_uint(xa[i]) << 1);
            xs[i] = xa[i] + sh;
        }
        const float* __restrict__ w = W1 + 72 * DIMF;
        #pragma unroll
        for (int k = 0; k < DIMF; ++k) {
            float acc = h[k];
            #pragma unroll
            for (int i = 0; i < 8; ++i)
                acc = fmaf(xs[i], w[i * DIMF + k], acc);
            h[k] = acc;
        }
    }
    {   // tail j = 80..82, fused relu
        float x0 = xg[80], x1 = xg[81], x2 = xg[82];
        nzbits |= (__float_as_uint(x0) << 1) | (__float_as_uint(x1) << 1)
                | (__float_as_uint(x2) << 1);
        const float s0 = x0 + sh, s1 = x1 + sh, s2 = x2 + sh;
        #pragma unroll
        for (int k = 0; k < DIMF; ++k) {
            float acc = h[k];
            acc = fmaf(s0, W1[80 * DIMF + k], acc);
            acc = fmaf(s1, W1[81 * DIMF + k], acc);
            acc = fmaf(s2, W1[82 * DIMF + k], acc);
            h[k] = fmaxf(acc, 0.0f);
        }
    }

    // ---- layer 2: g[32] = relu(h @ Wh0 + bh0), fully unrolled (static idx) ----
    float g[LAT];
    #pragma unroll
    for (int m = 0; m < LAT; ++m) g[m] = bh0[m];
    #pragma unroll
    for (int k = 0; k < DIMF; ++k) {
        #pragma unroll
        for (int m = 0; m < LAT; ++m)
            g[m] = fmaf(h[k], Wh0[k * LAT + m], g[m]);
    }
    #pragma unroll
    for (int m = 0; m < LAT; ++m) g[m] = fmaxf(g[m], 0.0f);

    // ---- layer 3: e[32] = relu(g @ Wh1 + bh1), fully unrolled ----
    float e[LAT];
    #pragma unroll
    for (int m = 0; m < LAT; ++m) e[m] = bh1[m];
    #pragma unroll
    for (int q = 0; q < LAT; ++q) {
        #pragma unroll
        for (int m = 0; m < LAT; ++m)
            e[m] = fmaf(g[q], Wh1[q * LAT + m], e[m]);
    }

    // ---- relu + L2 normalize + mask ----
    float ss = 0.0f;
    #pragma unroll
    for (int m = 0; m < LAT; ++m) {
        e[m] = fmaxf(e[m], 0.0f);
        ss = fmaf(e[m], e[m], ss);
    }
    const float scale = (nzbits != 0u) ? (1.0f / fmaxf(sqrtf(ss), 1e-12f)) : 0.0f;

    // ---- write 3 identical copies, float4 per thread ----
    float4 v[8];
    #pragma unroll
    for (int q = 0; q < 8; ++q) {
        v[q].x = e[q * 4 + 0] * scale;
        v[q].y = e[q * 4 + 1] * scale;
        v[q].z = e[q * 4 + 2] * scale;
        v[q].w = e[q * 4 + 3] * scale;
    }
    const long long obase = (long long)row * LAT;
    const long long osz   = (long long)nrows * LAT;
    float4* o0 = (float4*)(out + obase);
    float4* o1 = (float4*)(out + osz + obase);
    float4* o2 = (float4*)(out + 2 * osz + obase);
    #pragma unroll
    for (int q = 0; q < 8; ++q) o0[q] = v[q];
    #pragma unroll
    for (int q = 0; q < 8; ++q) o1[q] = v[q];
    #pragma unroll
    for (int q = 0; q < 8; ++q) o2[q] = v[q];
}

extern "C" void kernel_launch(void* const* d_in, const int* in_sizes, int n_in,
                              void* d_out, int out_size, void* d_ws, size_t ws_size,
                              hipStream_t stream) {
    const float* inp    = (const float*)d_in[0];
    const float* shiftp = (const float*)d_in[1];
    const float* W1     = (const float*)d_in[2];
    const float* b1     = (const float*)d_in[3];
    const float* Wh0    = (const float*)d_in[4];
    const float* bh0    = (const float*)d_in[5];
    const float* Wh1    = (const float*)d_in[6];
    const float* bh1    = (const float*)d_in[7];
    float* out = (float*)d_out;

    const int nrows = in_sizes[0] / FEAT;              // 2,000,000
    const int blocks = (nrows + THREADS - 1) / THREADS; // 7813

    material_encoder_kernel<<<dim3(blocks), dim3(THREADS), 0, stream>>>(
        inp, shiftp, W1, b1, Wh0, bh0, Wh1, bh1, out, nrows);
}